// Round 4
// baseline (92.707 us; speedup 1.0000x reference)
//
#include <hip/hip_runtime.h>
#include <stdint.h>
#include <string.h>

// R4 theory: inputs fp32, OUTPUT fp32 (E2). R1's inf = fp32-read-as-bf16 proof
// for inputs; R2/R3's bit-identical stub-signature failures = bf16 writes into
// an fp32 buffer (low half garbled <=6, max-ref position untouched). This
// round changes ONE variable vs R3: all out stores are fp32. LDS <= 34 KB
// (R1-proven budget), ws = 2.125 MB (R1-proven).

#define NN 512
#define NF 128
#define NC 64

typedef __attribute__((ext_vector_type(8))) short short8;
typedef __attribute__((ext_vector_type(4))) float f32x4;

__device__ __forceinline__ uint16_t f2bf(float f) {
    union { float f; uint32_t u; } v; v.f = f;
    uint32_t u = v.u;
    u += 0x7FFF + ((u >> 16) & 1);   // RNE
    return (uint16_t)(u >> 16);
}

// ---------------------------------------------------------------------------
// K1: feats = X @ kernels[h] via bf16 MFMA (fp32 inputs converted on load).
// Writes: a_s/a_n (fp32 ws), featw = feats^T bf16 [bh][c][n] (ws),
// relu(feats) = emb half of out (FP32). Grid 256 x 256. LDS 34 KB.
// ---------------------------------------------------------------------------
__global__ __launch_bounds__(256) void k1_feats(
    const float* __restrict__ X, const float* __restrict__ Kern,
    const float* __restrict__ a_self, const float* __restrict__ a_neigh,
    float* __restrict__ out, uint16_t* __restrict__ featw,
    float* __restrict__ asw, float* __restrict__ anw)
{
    __shared__ __align__(16) uint16_t Kt[64][136];  // kernels[h]^T bf16 [c][f]
    __shared__ float fs[64][65];                    // feats tile fp32 (pad 1)

    const int tid  = threadIdx.x;
    const int lane = tid & 63;
    const int wave = tid >> 6;
    const int blk  = blockIdx.x;
    const int nt   = blk & 7;
    const int bh   = blk >> 3;
    const int h    = bh & 3;
    const int b    = bh >> 2;
    const int nb   = nt * 64;

    // ---- stage Kt[c][f] = bf16(kernels[h][f][c]) ----
    {
        const int f0 = tid >> 1, c0 = (tid & 1) * 32;
        const float* kp = Kern + h * (NF * NC) + f0 * NC + c0;
        #pragma unroll
        for (int s4 = 0; s4 < 8; ++s4) {
            float4 v = *(const float4*)(kp + s4 * 4);
            Kt[c0 + s4 * 4 + 0][f0] = f2bf(v.x);
            Kt[c0 + s4 * 4 + 1][f0] = f2bf(v.y);
            Kt[c0 + s4 * 4 + 2][f0] = f2bf(v.z);
            Kt[c0 + s4 * 4 + 3][f0] = f2bf(v.w);
        }
    }

    // ---- A fragments: X rows, fp32 -> bf16 in registers ----
    const int m = lane & 15;
    const int q = lane >> 4;
    short8 af[4];
    {
        const float* xr = X + ((size_t)(b * NN) + nb + wave * 16 + m) * NF + q * 8;
        #pragma unroll
        for (int kt = 0; kt < 4; ++kt) {
            float4 x0 = *(const float4*)(xr + kt * 32);
            float4 x1 = *(const float4*)(xr + kt * 32 + 4);
            union { uint32_t u[4]; short8 s; } r;
            r.u[0] = (uint32_t)f2bf(x0.x) | ((uint32_t)f2bf(x0.y) << 16);
            r.u[1] = (uint32_t)f2bf(x0.z) | ((uint32_t)f2bf(x0.w) << 16);
            r.u[2] = (uint32_t)f2bf(x1.x) | ((uint32_t)f2bf(x1.y) << 16);
            r.u[3] = (uint32_t)f2bf(x1.z) | ((uint32_t)f2bf(x1.w) << 16);
            af[kt] = r.s;
        }
    }
    __syncthreads();

    // ---- MFMA: wave computes feats[16 rows x 64 c] ----
    #pragma unroll
    for (int ct = 0; ct < 4; ++ct) {
        f32x4 acc = {0.f, 0.f, 0.f, 0.f};
        #pragma unroll
        for (int kt = 0; kt < 4; ++kt) {
            short8 bfr;
            __builtin_memcpy(&bfr, &Kt[ct * 16 + m][kt * 32 + q * 8], 16);
            acc = __builtin_amdgcn_mfma_f32_16x16x32_bf16(af[kt], bfr, acc, 0, 0, 0);
        }
        #pragma unroll
        for (int r = 0; r < 4; ++r)
            fs[wave * 16 + q * 4 + r][ct * 16 + m] = acc[r];   // C: col=m, row=q*4+r
    }

    // ---- a_s / a_n: wave-local rows ----
    {
        const float asv = a_self[h * NC + lane];
        const float anv = a_neigh[h * NC + lane];
        for (int rr = 0; rr < 16; ++rr) {
            const int row = wave * 16 + rr;
            float f = fs[row][lane];
            float s1 = f * asv;
            float s2 = f * anv;
            #pragma unroll
            for (int off = 32; off > 0; off >>= 1) {
                s1 += __shfl_xor(s1, off);
                s2 += __shfl_xor(s2, off);
            }
            if (lane == 0) {
                asw[bh * NN + nb + row] = s1;
                anw[bh * NN + nb + row] = s2;
            }
        }
    }
    __syncthreads();   // fs complete for cross-wave reads

    // ---- emb half of out: relu(feats), FP32 float4 stores ----
    {
        const int row = tid >> 2, c0 = (tid & 3) * 16;
        float* ow = out + ((size_t)(b * NN) + nb + row) * 512 + h * NC + c0;
        #pragma unroll
        for (int e4 = 0; e4 < 4; ++e4) {
            float4 v;
            v.x = fmaxf(fs[row][c0 + e4 * 4 + 0], 0.f);
            v.y = fmaxf(fs[row][c0 + e4 * 4 + 1], 0.f);
            v.z = fmaxf(fs[row][c0 + e4 * 4 + 2], 0.f);
            v.w = fmaxf(fs[row][c0 + e4 * 4 + 3], 0.f);
            *(float4*)(ow + e4 * 4) = v;
        }
    }

    // ---- featw = feats^T bf16 [bh][c][n] ----
    {
        #pragma unroll
        for (int cc = 0; cc < 16; ++cc) {
            const int c = wave * 16 + cc;
            featw[((size_t)(bh * NC) + c) * NN + nb + lane] = f2bf(fs[lane][c]);
        }
    }
}

// ---------------------------------------------------------------------------
// K2: fused masked softmax + MFMA PV. P stays in registers (lane (m,q) owns
// exactly its A-frag slice P[m][q*8+j]). Max-free softmax (logits bounded
// ~|a_s|+|a_n| <= ~8; masked p = A*exp = exact 0); denominator at epilogue.
// Grid 512 x 128 (bh, it=32-row tile). LDS ~7.3 KB. Output FP32.
// ---------------------------------------------------------------------------
__global__ __launch_bounds__(128) void k2_attn(
    const float* __restrict__ A, const uint16_t* __restrict__ featw,
    const float* __restrict__ asw, const float* __restrict__ anw,
    const float* __restrict__ biases, float* __restrict__ out)
{
    __shared__ __align__(16) uint16_t Vt[64][40];  // feats^T chunk [c][32 j]
    __shared__ __align__(16) float anl[NN];
    __shared__ float s_lds[2][16];

    const int tid  = threadIdx.x;
    const int lane = tid & 63;
    const int wave = tid >> 6;
    const int blk  = blockIdx.x;
    const int it   = blk & 15;
    const int bh   = blk >> 4;
    const int h    = bh & 3;
    const int b    = bh >> 2;
    const int m    = lane & 15;
    const int q    = lane >> 4;
    const int i    = it * 32 + wave * 16 + m;     // this lane's attention row

    anl[tid]       = anw[bh * NN + tid];
    anl[tid + 128] = anw[bh * NN + tid + 128];
    anl[tid + 256] = anw[bh * NN + tid + 256];
    anl[tid + 384] = anw[bh * NN + tid + 384];

    const float a_si = asw[bh * NN + i];
    const float* Ab  = A + (size_t)b * NN * NN + (size_t)i * NN;

    f32x4 acc[4];
    #pragma unroll
    for (int ct = 0; ct < 4; ++ct) { acc[ct][0]=0.f; acc[ct][1]=0.f; acc[ct][2]=0.f; acc[ct][3]=0.f; }
    float ssum = 0.f;

    // A prefetch (chunk 0)
    float4 a0 = *(const float4*)(Ab + q * 8);
    float4 a1 = *(const float4*)(Ab + q * 8 + 4);

    // staging roles: thread -> (c, j-offset)
    const int sc = tid >> 1;
    const int sj = (tid & 1) * 16;
    const uint16_t* fwp = featw + ((size_t)(bh * NC) + sc) * NN + sj;

    for (int ch = 0; ch < 16; ++ch) {
        // ---- stage Vt = feats^T[:, ch*32 .. +32] ----
        uint4 f0 = *(const uint4*)(fwp + ch * 32);
        uint4 f1 = *(const uint4*)(fwp + ch * 32 + 8);
        *(uint4*)&Vt[sc][sj]     = f0;
        *(uint4*)&Vt[sc][sj + 8] = f1;
        __syncthreads();

        // ---- prefetch next A chunk ----
        const int nxt = (ch < 15) ? ch + 1 : 15;
        float4 na0 = *(const float4*)(Ab + nxt * 32 + q * 8);
        float4 na1 = *(const float4*)(Ab + nxt * 32 + q * 8 + 4);

        // ---- p for j = ch*32 + q*8 .. +8 ----
        float4 n0 = *(const float4*)&anl[ch * 32 + q * 8];
        float4 n1 = *(const float4*)&anl[ch * 32 + q * 8 + 4];
        float an[8] = {n0.x, n0.y, n0.z, n0.w, n1.x, n1.y, n1.z, n1.w};
        float aj[8] = {a0.x, a0.y, a0.z, a0.w, a1.x, a1.y, a1.z, a1.w};
        float pv[8];
        #pragma unroll
        for (int k = 0; k < 8; ++k) {
            float e = a_si + an[k];
            float l = fmaxf(e, 0.2f * e);          // LeakyReLU(0.2)
            pv[k] = aj[k] * __expf(l);             // A in {0,1}: exact mask
            ssum += pv[k];
        }
        union { uint32_t u[4]; short8 s; } afu;
        afu.u[0] = (uint32_t)f2bf(pv[0]) | ((uint32_t)f2bf(pv[1]) << 16);
        afu.u[1] = (uint32_t)f2bf(pv[2]) | ((uint32_t)f2bf(pv[3]) << 16);
        afu.u[2] = (uint32_t)f2bf(pv[4]) | ((uint32_t)f2bf(pv[5]) << 16);
        afu.u[3] = (uint32_t)f2bf(pv[6]) | ((uint32_t)f2bf(pv[7]) << 16);
        short8 afrg = afu.s;

        // ---- PV MFMA: acc[ct] += P(16x32) * V(32x16c) ----
        #pragma unroll
        for (int ct = 0; ct < 4; ++ct) {
            short8 bfr;
            __builtin_memcpy(&bfr, &Vt[ct * 16 + m][q * 8], 16);
            acc[ct] = __builtin_amdgcn_mfma_f32_16x16x32_bf16(afrg, bfr, acc[ct], 0, 0, 0);
        }
        __syncthreads();   // Vt reads done before next stage
        a0 = na0; a1 = na1;
    }

    // ---- softmax denominator: reduce over q groups; route via LDS ----
    ssum += __shfl_xor(ssum, 16);
    ssum += __shfl_xor(ssum, 32);
    if (lane < 16) s_lds[wave][lane] = ssum;   // lane<16 has m=lane

    // ---- epilogue: scale, bias, relu, FP32 store (agg half) ----
    #pragma unroll
    for (int ct = 0; ct < 4; ++ct) {
        const float bias_c = biases[h * NC + ct * 16 + m];
        #pragma unroll
        for (int r = 0; r < 4; ++r) {
            const int row = q * 4 + r;                 // C: col=m, row=q*4+r
            const float sinv = 1.f / s_lds[wave][row];
            float o = fmaxf(acc[ct][r] * sinv + bias_c, 0.f);
            const int gi = it * 32 + wave * 16 + row;
            out[((size_t)(b * NN) + gi) * 512 + 256 + h * NC + ct * 16 + m] = o;
        }
    }
}

// ---------------------------------------------------------------------------
extern "C" void kernel_launch(void* const* d_in, const int* in_sizes, int n_in,
                              void* d_out, int out_size, void* d_ws, size_t ws_size,
                              hipStream_t stream) {
    (void)in_sizes; (void)n_in; (void)out_size; (void)ws_size;
    const float* X       = (const float*)d_in[0];
    const float* A       = (const float*)d_in[1];
    const float* Kern    = (const float*)d_in[2];
    const float* biases  = (const float*)d_in[3];
    const float* a_self  = (const float*)d_in[4];
    const float* a_neigh = (const float*)d_in[5];
    float* out = (float*)d_out;

    uint16_t* featw = (uint16_t*)d_ws;                          // 2 MB bf16 feats^T
    float* asw = (float*)((char*)d_ws + 2097152);               // 64 KB
    float* anw = (float*)((char*)d_ws + 2097152 + 65536);       // 64 KB
    // total 2.125 MB (R1-proven ws footprint)

    hipLaunchKernelGGL(k1_feats, dim3(256), dim3(256), 0, stream,
                       X, Kern, a_self, a_neigh, out, featw, asw, anw);
    hipLaunchKernelGGL(k2_attn, dim3(512), dim3(128), 0, stream,
                       A, featw, asw, anw, biases, out);
}